// Round 1
// baseline (152.629 us; speedup 1.0000x reference)
//
#include <hip/hip_runtime.h>
#include <hip/hip_bf16.h>

// Shift SSM == causal 64-tap FIR per channel + skip connection.
//   K[h,k] = sum_{s=0}^{63-k} B[h,s] * C[0,h,k+s]   (cross-correlation)
//   y[b,h,l] = sum_{k=0}^{63} K[h,k] * u[b,h,l-k] + D[h]*u[b,h,l]
// D[h] is folded into K[h,0].

#define D_MODEL 512
#define D_STATE 64
#define BATCH   8
#define SEQ_L   4096

// ---- Kernel 1: compute FIR taps into workspace (512 x 64 floats) ----
__global__ void shift_taps_kernel(const float* __restrict__ B,
                                  const float* __restrict__ C,
                                  const float* __restrict__ D,
                                  float* __restrict__ K) {
    const int h = blockIdx.x;        // 0..511
    const int k = threadIdx.x;       // 0..63
    const float* Bh = B + h * D_STATE;
    const float* Ch = C + h * D_STATE;
    float s = 0.f;
    for (int j = 0; j + k < D_STATE; ++j)
        s = fmaf(Bh[j], Ch[k + j], s);
    if (k == 0) s += D[h];           // fold skip connection into tap 0
    K[h * D_STATE + k] = s;
}

// ---- Kernel 2: 64-tap causal FIR over each (b,h) row of length 4096 ----
// One block per row. 256 threads x 16 outputs each. Each thread holds an
// 80-float window in registers (loaded as aligned float4; the 5x overlap
// between neighboring threads is served by L1/L2, not HBM).
__global__ void __launch_bounds__(256)
shift_fir_kernel(const float* __restrict__ u,
                 const float* __restrict__ taps,
                 float* __restrict__ y) {
    const int row = blockIdx.x;              // b*512 + h
    const int h   = row & (D_MODEL - 1);
    const float* __restrict__ urow = u + (size_t)row * SEQ_L;
    float* __restrict__ yrow       = y + (size_t)row * SEQ_L;

    __shared__ float K[D_STATE];
    if (threadIdx.x < D_STATE) K[threadIdx.x] = taps[h * D_STATE + threadIdx.x];
    __syncthreads();

    const int t    = threadIdx.x;            // 0..255
    const int out0 = t * 16;                 // first output this thread owns
    const int start = out0 - 64;             // window start (multiple of 16)

    float win[80];
    #pragma unroll
    for (int j = 0; j < 20; ++j) {
        const int idx = start + 4 * j;       // aligned: entirely <0 or >=0
        if (idx >= 0) {
            const float4 v = *(const float4*)(urow + idx);
            win[4*j + 0] = v.x; win[4*j + 1] = v.y;
            win[4*j + 2] = v.z; win[4*j + 3] = v.w;
        } else {
            win[4*j + 0] = 0.f; win[4*j + 1] = 0.f;
            win[4*j + 2] = 0.f; win[4*j + 3] = 0.f;
        }
    }

    float acc[16];
    #pragma unroll
    for (int i = 0; i < 16; ++i) acc[i] = 0.f;

    #pragma unroll
    for (int k = 0; k < D_STATE; ++k) {
        const float Kk = K[k];               // LDS broadcast (conflict-free)
        #pragma unroll
        for (int i = 0; i < 16; ++i)
            acc[i] = fmaf(Kk, win[64 + i - k], acc[i]);
    }

    #pragma unroll
    for (int j = 0; j < 4; ++j) {
        float4 o;
        o.x = acc[4*j + 0]; o.y = acc[4*j + 1];
        o.z = acc[4*j + 2]; o.w = acc[4*j + 3];
        *(float4*)(yrow + out0 + 4*j) = o;
    }
}

extern "C" void kernel_launch(void* const* d_in, const int* in_sizes, int n_in,
                              void* d_out, int out_size, void* d_ws, size_t ws_size,
                              hipStream_t stream) {
    const float* u = (const float*)d_in[0];   // (8, 512, 4096)
    const float* B = (const float*)d_in[1];   // (512, 64)
    const float* C = (const float*)d_in[2];   // (1, 512, 64)
    const float* D = (const float*)d_in[3];   // (512,)
    float* y    = (float*)d_out;              // (8, 512, 4096)
    float* taps = (float*)d_ws;               // 512*64 floats = 128 KB

    shift_taps_kernel<<<dim3(D_MODEL), dim3(D_STATE), 0, stream>>>(B, C, D, taps);
    shift_fir_kernel<<<dim3(BATCH * D_MODEL), dim3(256), 0, stream>>>(u, taps, y);
}

// Round 2
// 138.941 us; speedup vs baseline: 1.0985x; 1.0985x over previous
//
#include <hip/hip_runtime.h>
#include <hip/hip_bf16.h>

// Shift SSM == causal 64-tap FIR per channel + skip connection.
//   K[h,k] = sum_{s=0}^{63-k} B[h,s] * C[0,h,k+s]
//   y[b,h,l] = sum_{k=0}^{63} K[h,k] * u[b,h,l-k] + D[h]*u[b,h,l]
// D folded into K[h,0]. Single fused kernel: wave0 computes taps while all
// waves stage the u row into LDS; compute reads 32-float window chunks from
// LDS (XOR-swizzled float4 layout -> conflict-free b128 reads at 64B lane
// stride) keeping only win[32]+acc[16] in registers (no spills).

#define D_MODEL 512
#define D_STATE 64
#define BATCH   8
#define SEQ_L   4096
#define NT      256

// XOR swizzle at float4-group granularity: preserves 16B alignment, spreads
// 64B-strided lane accesses across all 8 bank-quads.
__device__ __forceinline__ int SW(int g) { return g ^ ((g >> 3) & 7); }

__global__ void __launch_bounds__(NT)
shift_fused_kernel(const float* __restrict__ u,
                   const float* __restrict__ B,
                   const float* __restrict__ C,
                   const float* __restrict__ D,
                   float* __restrict__ y) {
    const int row = blockIdx.x;              // b*512 + h
    const int h   = row & (D_MODEL - 1);
    const float* __restrict__ urow = u + (size_t)row * SEQ_L;
    float* __restrict__ yrow       = y + (size_t)row * SEQ_L;

    __shared__ float  K[D_STATE];
    __shared__ float4 su4[(D_STATE + SEQ_L) / 4];   // 1040 groups, swizzled

    const int t = threadIdx.x;

    // --- zero halo: logical floats [0,64) = groups 0..15 ---
    if (t < 16) su4[SW(t)] = make_float4(0.f, 0.f, 0.f, 0.f);

    // --- stage u row: 4 coalesced float4 loads per thread ---
    #pragma unroll
    for (int j = 0; j < 4; ++j) {
        const int e = t + NT * j;                    // float4 index in row
        const float4 v = *(const float4*)(urow + 4 * e);
        su4[SW(16 + e)] = v;                         // halo offset = 16 groups
    }

    // --- taps on wave 0 (overlaps with staging by other waves) ---
    if (t < D_STATE) {
        const float* Bh = B + h * D_STATE;
        const float* Ch = C + h * D_STATE;
        float s = 0.f;
        #pragma unroll
        for (int j = 0; j < D_STATE; ++j) {
            const int c = t + j;
            float bv = Bh[j];
            const float cv = Ch[c & (D_STATE - 1)]; // clamped: no OOB load
            if (c >= D_STATE) bv = 0.f;
            s = fmaf(bv, cv, s);
        }
        if (t == 0) s += D[h];
        K[t] = s;
    }
    __syncthreads();

    // --- FIR: thread t owns outputs [16t, 16t+16) ---
    const int out0 = t * 16;
    const float* sf = (const float*)su4;

    float acc[16];
    #pragma unroll
    for (int i = 0; i < 16; ++i) acc[i] = 0.f;

    #pragma unroll
    for (int kk = 0; kk < 4; ++kk) {
        // window logical floats [base, base+32), base multiple of 16
        const int base = out0 + 48 - 16 * kk;        // in [0, 4128]
        const int g0   = base >> 2;                  // first float4 group
        float win[32];
        #pragma unroll
        for (int w = 0; w < 8; ++w) {
            const float4 v = *(const float4*)(sf + 4 * SW(g0 + w));
            win[4*w + 0] = v.x; win[4*w + 1] = v.y;
            win[4*w + 2] = v.z; win[4*w + 3] = v.w;
        }
        #pragma unroll
        for (int q = 0; q < 16; ++q) {
            const float Kv = K[16 * kk + q];         // LDS broadcast, free
            #pragma unroll
            for (int i = 0; i < 16; ++i)
                acc[i] = fmaf(Kv, win[16 + i - q], acc[i]);
        }
    }

    #pragma unroll
    for (int j = 0; j < 4; ++j) {
        float4 o;
        o.x = acc[4*j + 0]; o.y = acc[4*j + 1];
        o.z = acc[4*j + 2]; o.w = acc[4*j + 3];
        *(float4*)(yrow + out0 + 4*j) = o;
    }
}

extern "C" void kernel_launch(void* const* d_in, const int* in_sizes, int n_in,
                              void* d_out, int out_size, void* d_ws, size_t ws_size,
                              hipStream_t stream) {
    const float* u = (const float*)d_in[0];   // (8, 512, 4096)
    const float* B = (const float*)d_in[1];   // (512, 64)
    const float* C = (const float*)d_in[2];   // (1, 512, 64)
    const float* D = (const float*)d_in[3];   // (512,)
    float* y = (float*)d_out;                 // (8, 512, 4096)

    shift_fused_kernel<<<dim3(BATCH * D_MODEL), dim3(NT), 0, stream>>>(u, B, C, D, y);
}